// Round 9
// baseline (215.382 us; speedup 1.0000x reference)
//
#include <hip/hip_runtime.h>
#include <hip/hip_bf16.h>
#include <math.h>

// Problem constants (match reference setup_inputs)
#define B_SZ   2
#define N_SEQ  2048
#define C_DIM  1024
#define H_NUM  16
#define D_HEAD 64
#define M_ROWS (B_SZ * N_SEQ)   // 4096
#define QKV_N  (3 * C_DIM)      // 3072

typedef __attribute__((ext_vector_type(8))) short  bf16x8;
typedef __attribute__((ext_vector_type(4))) float  floatx4;

// fp32 -> bf16 bits, round-to-nearest-even
static __device__ __forceinline__ unsigned short f2bf(float x) {
    unsigned int u = __float_as_uint(x);
    u = (u + 0x7FFFu + ((u >> 16) & 1u)) >> 16;
    return (unsigned short)u;
}
// RNE-rounded bits kept in the high halfword (for pair packing via v_perm)
static __device__ __forceinline__ unsigned int f2bf_hi(float x) {
    unsigned int u = __float_as_uint(x);
    return u + 0x7FFFu + ((u >> 16) & 1u);
}

#if __has_builtin(__builtin_amdgcn_exp2f)
#define EXP2F(x) __builtin_amdgcn_exp2f(x)
#else
#define EXP2F(x) exp2f(x)
#endif

#define GLP(p) ((const __attribute__((address_space(1))) void*)(p))
#define LDP(p) ((__attribute__((address_space(3))) void*)(p))

#define CEXP 0.18033688011112042f   // 0.125 * log2(e)

// ---------------------------------------------------------------------------
// Fused prep (1 launch): blocks [0,4096) convert x to bf16;
// [4096,4864) transpose-convert w_qkv; [4864,5120) transpose-convert w_proj.
// ---------------------------------------------------------------------------
__global__ __launch_bounds__(256)
void prep_fused(const float* __restrict__ x,      unsigned short* __restrict__ xb,
                const float* __restrict__ w_qkv,  unsigned short* __restrict__ wqkvT,
                const float* __restrict__ w_proj, unsigned short* __restrict__ wprojT)
{
    __shared__ unsigned short t[64][72];
    const int bid = blockIdx.x;
    const int tid = threadIdx.x;

    if (bid < 4096) {                        // x -> bf16 (exactly 1M float4 groups)
        const int i = bid * 256 + tid;
        float4 v = ((const float4*)x)[i];
        ushort4 p;
        p.x = f2bf(v.x); p.y = f2bf(v.y); p.z = f2bf(v.z); p.w = f2bf(v.w);
        ((ushort4*)xb)[i] = p;
        return;
    }

    const float* W;
    unsigned short* WT;
    int N, tt;
    if (bid < 4096 + 768) { W = w_qkv;  WT = wqkvT;  N = QKV_N; tt = bid - 4096; }
    else                  { W = w_proj; WT = wprojT; N = C_DIM; tt = bid - 4864; }
    const int ntiles = N / 64;
    const int n0 = (tt % ntiles) * 64;
    const int k0 = (tt / ntiles) * 64;
    const int K  = C_DIM;

    const int tc = tid & 15;
    const int tr = tid >> 4;
    #pragma unroll
    for (int p = 0; p < 4; ++p) {
        const int r = tr + p * 16;
        float4 v = *(const float4*)&W[(size_t)(k0 + r) * N + n0 + tc * 4];
        ushort4 pk;
        pk.x = f2bf(v.x); pk.y = f2bf(v.y); pk.z = f2bf(v.z); pk.w = f2bf(v.w);
        *(ushort4*)&t[r][tc * 4] = pk;
    }
    __syncthreads();

    const int n  = tid >> 2;
    const int c0 = (tid & 3) * 16;
    unsigned short tmp[16];
    #pragma unroll
    for (int i = 0; i < 16; ++i) tmp[i] = t[c0 + i][n];
    *(uint4*)&WT[(size_t)(n0 + n) * K + k0 + c0]     = *(uint4*)&tmp[0];
    *(uint4*)&WT[(size_t)(n0 + n) * K + k0 + c0 + 8] = *(uint4*)&tmp[8];
}

// ---------------------------------------------------------------------------
// QKV GEMM (m97 structure), split by region so the K-loop is branch-free.
// SWAP=true  (q/k, bn<2048): swapped-operand MFMA -> lane holds 4 consecutive
//   d at fixed n -> ushort4 stores into qbuf/kbuf[(b,h)][n][d]; q scaled CEXP.
// SWAP=false (v, bn>=2048): normal order -> ushort4-along-n stores into
//   vbuf[(b,h)][d][n'] (keys permuted per-64:
//   fk = (a&0x20)|((a&0x0C)<<1)|((a&0x10)>>2)|(a&3))
// ---------------------------------------------------------------------------
template <bool SWAP>
__global__ __launch_bounds__(256)
void gemm_qkv_part(const unsigned short* __restrict__ A,   // xb [4096][1024]
                   const unsigned short* __restrict__ BT,  // wqkvT [3072][1024]
                   unsigned short* __restrict__ qbuf,
                   unsigned short* __restrict__ kbuf,
                   unsigned short* __restrict__ vbuf)
{
    const int K = C_DIM;
    __shared__ unsigned short As[128 * 32];
    __shared__ unsigned short Bs[128 * 32];

    const int tid  = threadIdx.x;
    const int lane = tid & 63;
    const int wave = tid >> 6;
    const int l15  = lane & 15;
    const int lq   = lane >> 4;
    const int wm   = (wave & 1) * 64;
    const int wn   = (wave >> 1) * 64;

    const int bm = blockIdx.y * 128;
    const int bn = (SWAP ? 0 : 2 * C_DIM) + blockIdx.x * 128;

    const int sr = tid >> 2;
    const int sc = (tid & 3) * 8;

    const unsigned short* ga0 = A  + (size_t)(bm + sr) * K + sc;
    const unsigned short* ga1 = A  + (size_t)(bm + 64 + sr) * K + sc;
    const unsigned short* gb0 = BT + (size_t)(bn + sr) * K + sc;
    const unsigned short* gb1 = BT + (size_t)(bn + 64 + sr) * K + sc;

    unsigned short* la0 = &As[sr * 32 + sc];
    unsigned short* la1 = &As[(64 + sr) * 32 + sc];
    unsigned short* lb0 = &Bs[sr * 32 + sc];
    unsigned short* lb1 = &Bs[(64 + sr) * 32 + sc];

    floatx4 acc[4][4];
    #pragma unroll
    for (int i = 0; i < 4; ++i)
        #pragma unroll
        for (int j = 0; j < 4; ++j) acc[i][j] = (floatx4){0.f, 0.f, 0.f, 0.f};

    for (int kt = 0; kt < K; kt += 32) {
        __builtin_amdgcn_global_load_lds(GLP(ga0), LDP(la0), 16, 0, 0);
        __builtin_amdgcn_global_load_lds(GLP(ga1), LDP(la1), 16, 0, 0);
        __builtin_amdgcn_global_load_lds(GLP(gb0), LDP(lb0), 16, 0, 0);
        __builtin_amdgcn_global_load_lds(GLP(gb1), LDP(lb1), 16, 0, 0);
        ga0 += 32; ga1 += 32; gb0 += 32; gb1 += 32;
        __syncthreads();

        bf16x8 af[4], bfr[4];
        #pragma unroll
        for (int t = 0; t < 4; ++t) {
            af[t]  = *(const bf16x8*)&As[(wm + t * 16 + l15) * 32 + lq * 8];
            bfr[t] = *(const bf16x8*)&Bs[(wn + t * 16 + l15) * 32 + lq * 8];
        }
        #pragma unroll
        for (int mt = 0; mt < 4; ++mt)
            #pragma unroll
            for (int nt = 0; nt < 4; ++nt)
                acc[mt][nt] = SWAP
                    ? __builtin_amdgcn_mfma_f32_16x16x32_bf16(bfr[nt], af[mt], acc[mt][nt], 0, 0, 0)
                    : __builtin_amdgcn_mfma_f32_16x16x32_bf16(af[mt], bfr[nt], acc[mt][nt], 0, 0, 0);
        __syncthreads();
    }

    if (SWAP) {
        // q/k: per tile D = C^T -> lane holds 4 consecutive d (rows) at fixed n (col)
        const bool isq = (bn < C_DIM);
        const float scq = isq ? CEXP : 1.0f;
        unsigned short* dbuf = isq ? qbuf : kbuf;
        #pragma unroll
        for (int nt = 0; nt < 4; ++nt) {
            const int colb = bn + wn + nt * 16 + lq * 4;
            const int h    = (colb >> 6) & 15;
            const int d    = colb & 63;
            #pragma unroll
            for (int mt = 0; mt < 4; ++mt) {
                const int row = bm + wm + mt * 16 + l15;
                const int b   = row >> 11;
                const int n   = row & 2047;
                ushort4 pk;
                pk.x = f2bf(acc[mt][nt][0] * scq);
                pk.y = f2bf(acc[mt][nt][1] * scq);
                pk.z = f2bf(acc[mt][nt][2] * scq);
                pk.w = f2bf(acc[mt][nt][3] * scq);
                *(ushort4*)&dbuf[((size_t)(b * H_NUM + h) * N_SEQ + n) * D_HEAD + d] = pk;
            }
        }
    } else {
        // v: lane holds 4 consecutive n (rows) at fixed d (col)
        #pragma unroll
        for (int nt = 0; nt < 4; ++nt) {
            const int col = bn + wn + nt * 16 + l15;
            const int h   = (col >> 6) & 15;
            const int d   = col & 63;
            #pragma unroll
            for (int mt = 0; mt < 4; ++mt) {
                const int row = bm + wm + mt * 16 + lq * 4;   // multiple of 4
                const int b   = row >> 11;
                const int n   = row & 2047;
                const int a   = n & 63;   // low 2 bits zero
                const int fk  = (a & 0x20) | ((a & 0x0C) << 1) | ((a & 0x10) >> 2);
                ushort4 pk;
                pk.x = f2bf(acc[mt][nt][0]); pk.y = f2bf(acc[mt][nt][1]);
                pk.z = f2bf(acc[mt][nt][2]); pk.w = f2bf(acc[mt][nt][3]);
                *(ushort4*)&vbuf[((size_t)(b * H_NUM + h) * D_HEAD + d) * N_SEQ
                                 + (n & ~63) + fk] = pk;
            }
        }
    }
}

// ---------------------------------------------------------------------------
// S^T-form bf16 MFMA flash attention, fixed-max softmax, no P round-trip.
// Block = 4 waves; wave = 16 q-rows; grid = 32 bh x 32 qblk = 1024 blocks
// (4 blocks/CU). 64-key double-buffered LDS tiles via global_load_lds with
// XOR segment swizzle. q pre-scaled by CEXP; S-acc init -8 folds the shift.
// ---------------------------------------------------------------------------
__global__ __launch_bounds__(256)
void attn_mfma(const unsigned short* __restrict__ qbuf,
               const unsigned short* __restrict__ kbuf,
               const unsigned short* __restrict__ vbuf,
               unsigned short* __restrict__ attnb)
{
    __shared__ unsigned short KsS[2][64 * 64];
    __shared__ unsigned short VtS[2][64 * 64];

    const int tid  = threadIdx.x;
    const int lane = tid & 63;
    const int wave = tid >> 6;
    const int l15  = lane & 15;
    const int lq   = lane >> 4;
    const int e    = l15 & 7;

    // XCD swizzle: low 3 bits pick XCD; keep same bh within one XCD group
    const int bid  = blockIdx.x;                    // 0..1023
    const int bh   = (bid & 7) * 4 + (bid >> 8);    // 0..31
    const int qblk = (bid >> 3) & 31;               // 0..31
    const int b    = bh >> 4;
    const int h    = bh & 15;
    const int q0   = qblk * 64 + wave * 16;

    const unsigned short* khead = kbuf + (size_t)bh * N_SEQ * D_HEAD;
    const unsigned short* vhead = vbuf + (size_t)bh * D_HEAD * N_SEQ;

    // Q B-frags (q pre-scaled by CEXP at gemm_qkv)
    bf16x8 qf[2];
    {
        const unsigned short* qrow = qbuf
            + ((size_t)bh * N_SEQ + q0 + l15) * D_HEAD + lq * 8;
        qf[0] = *(const bf16x8*)qrow;
        qf[1] = *(const bf16x8*)(qrow + 32);
    }

    floatx4 acc[4];
    #pragma unroll
    for (int dc = 0; dc < 4; ++dc) acc[dc] = (floatx4){0.f, 0.f, 0.f, 0.f};
    float lsum = 0.f;

    // staging: row = tid>>3 (0..31), seg = tid&7, global seg = seg^(row&7)
    const int srow = tid >> 3;
    const int gso  = ((tid & 7) ^ (srow & 7)) * 8;

    // prologue: stage tile 0 into buffer 0
    __builtin_amdgcn_global_load_lds(GLP(khead + (size_t)srow * 64 + gso),
                                     LDP(&KsS[0][tid * 8]), 16, 0, 0);
    __builtin_amdgcn_global_load_lds(GLP(khead + (size_t)(srow + 32) * 64 + gso),
                                     LDP(&KsS[0][2048 + tid * 8]), 16, 0, 0);
    __builtin_amdgcn_global_load_lds(GLP(vhead + (size_t)srow * N_SEQ + gso),
                                     LDP(&VtS[0][tid * 8]), 16, 0, 0);
    __builtin_amdgcn_global_load_lds(GLP(vhead + (size_t)(srow + 32) * N_SEQ + gso),
                                     LDP(&VtS[0][2048 + tid * 8]), 16, 0, 0);

    for (int tile = 0; tile < N_SEQ / 64; ++tile) {
        const int cur = tile & 1;
        __syncthreads();   // drains DMA for cur; prior reads of cur^1 done

        if (tile + 1 < N_SEQ / 64) {
            const int m1 = (tile + 1) * 64;
            const int nx = cur ^ 1;
            __builtin_amdgcn_global_load_lds(GLP(khead + (size_t)(m1 + srow) * 64 + gso),
                                             LDP(&KsS[nx][tid * 8]), 16, 0, 0);
            __builtin_amdgcn_global_load_lds(GLP(khead + (size_t)(m1 + srow + 32) * 64 + gso),
                                             LDP(&KsS[nx][2048 + tid * 8]), 16, 0, 0);
            __builtin_amdgcn_global_load_lds(GLP(vhead + (size_t)srow * N_SEQ + m1 + gso),
                                             LDP(&VtS[nx][tid * 8]), 16, 0, 0);
            __builtin_amdgcn_global_load_lds(GLP(vhead + (size_t)(srow + 32) * N_SEQ + m1 + gso),
                                             LDP(&VtS[nx][2048 + tid * 8]), 16, 0, 0);
        }

        const unsigned short* Ksc = &KsS[cur][0];
        const unsigned short* Vtc = &VtS[cur][0];

        // S^T = K Q^T (acc init -8 folds the softmax shift)
        floatx4 st[4];
        #pragma unroll
        for (int t = 0; t < 4; ++t) {
            bf16x8 k0 = *(const bf16x8*)&Ksc[(t * 16 + l15) * 64 + ((lq ^ e) * 8)];
            bf16x8 k1 = *(const bf16x8*)&Ksc[(t * 16 + l15) * 64 + (((4 + lq) ^ e) * 8)];
            floatx4 s = (floatx4){-8.f, -8.f, -8.f, -8.f};
            s = __builtin_amdgcn_mfma_f32_16x16x32_bf16(k0, qf[0], s, 0, 0, 0);
            s = __builtin_amdgcn_mfma_f32_16x16x32_bf16(k1, qf[1], s, 0, 0, 0);
            st[t] = s;
        }

        // fixed-max softmax: p = 2^st; RNE pair-pack via v_perm
        unsigned int pk[8];
        float la = 0.f;
        #pragma unroll
        for (int t = 0; t < 4; ++t) {
            float p0 = EXP2F(st[t][0]);
            float p1 = EXP2F(st[t][1]);
            float p2 = EXP2F(st[t][2]);
            float p3 = EXP2F(st[t][3]);
            la += (p0 + p1) + (p2 + p3);
            pk[t * 2]     = __builtin_amdgcn_perm(f2bf_hi(p1), f2bf_hi(p0), 0x07060302u);
            pk[t * 2 + 1] = __builtin_amdgcn_perm(f2bf_hi(p3), f2bf_hi(p2), 0x07060302u);
        }
        lsum += la;
        union { uint4 u; bf16x8 v; } cvt0, cvt1;
        cvt0.u = make_uint4(pk[0], pk[1], pk[2], pk[3]);
        cvt1.u = make_uint4(pk[4], pk[5], pk[6], pk[7]);

        // O^T += V^T P^T (keys permuted consistently via vbuf layout)
        #pragma unroll
        for (int dc = 0; dc < 4; ++dc) {
            bf16x8 v0 = *(const bf16x8*)&Vtc[(dc * 16 + l15) * 64 + ((lq ^ e) * 8)];
            bf16x8 v1 = *(const bf16x8*)&Vtc[(dc * 16 + l15) * 64 + (((4 + lq) ^ e) * 8)];
            acc[dc] = __builtin_amdgcn_mfma_f32_16x16x32_bf16(v0, cvt0.v, acc[dc], 0, 0, 0);
            acc[dc] = __builtin_amdgcn_mfma_f32_16x16x32_bf16(v1, cvt1.v, acc[dc], 0, 0, 0);
        }
    }

    // epilogue: reduce l across lq groups, normalize, store bf16
    float l = lsum;
    l += __shfl_xor(l, 16, 64);
    l += __shfl_xor(l, 32, 64);
    const float inv = 1.f / l;
    const int q = q0 + l15;
    unsigned short* orow = attnb + ((size_t)b * N_SEQ + q) * C_DIM + h * D_HEAD;
    #pragma unroll
    for (int dc = 0; dc < 4; ++dc) {
        ushort4 pkk;
        pkk.x = f2bf(acc[dc][0] * inv);
        pkk.y = f2bf(acc[dc][1] * inv);
        pkk.z = f2bf(acc[dc][2] * inv);
        pkk.w = f2bf(acc[dc][3] * inv);
        *(ushort4*)&orow[dc * 16 + lq * 4] = pkk;
    }
}

// ---------------------------------------------------------------------------
// bf16 GEMM for the output projection: 128(M) x 64(N) tile, BK=32.
// Grid (N/64, M/128) = 512 blocks -> 2 blocks/CU.
// ---------------------------------------------------------------------------
__global__ __launch_bounds__(256)
void gemm_bt(const unsigned short* __restrict__ A,   // [M][K] bf16
             const unsigned short* __restrict__ BT,  // [N][K] bf16
             const float* __restrict__ bias,         // [N] fp32
             float* __restrict__ Cm,
             int M, int N, int K)
{
    __shared__ unsigned short As[128 * 32];
    __shared__ unsigned short Bs[64 * 32];

    const int tid  = threadIdx.x;
    const int lane = tid & 63;
    const int wave = tid >> 6;
    const int l15  = lane & 15;
    const int lq   = lane >> 4;
    const int wm   = (wave & 1) * 64;
    const int wn   = (wave >> 1) * 32;

    const int bm = blockIdx.y * 128;
    const int bn = blockIdx.x * 64;

    const int sr = tid >> 2;
    const int sc = (tid & 3) * 8;

    const unsigned short* ga0 = A  + (size_t)(bm + sr) * K + sc;
    const unsigned short* ga1 = A  + (size_t)(bm + 64 + sr) * K + sc;
    const unsigned short* gb0 = BT + (size_t)(bn + sr) * K + sc;

    unsigned short* la0 = &As[sr * 32 + sc];
    unsigned short* la1 = &As[(64 + sr) * 32 + sc];
    unsigned short* lb0 = &Bs[sr * 32 + sc];

    floatx4 acc[4][2];
    #pragma unroll
    for (int i = 0; i < 4; ++i)
        #pragma unroll
        for (int j = 0; j < 2; ++j) acc[i][j] = (floatx4){0.f, 0.f, 0.f, 0.f};

    for (int kt = 0; kt < K; kt += 32) {
        __builtin_amdgcn_global_load_lds(GLP(ga0), LDP(la0), 16, 0, 0);
        __builtin_amdgcn_global_load_lds(GLP(ga1), LDP(la1), 16, 0, 0);
        __builtin_amdgcn_global_load_lds(GLP(gb0), LDP(lb0), 16, 0, 0);
        ga0 += 32; ga1 += 32; gb0 += 32;
        __syncthreads();

        bf16x8 af[4], bfr[2];
        #pragma unroll
        for (int t = 0; t < 4; ++t)
            af[t] = *(const bf16x8*)&As[(wm + t * 16 + l15) * 32 + lq * 8];
        #pragma unroll
        for (int t = 0; t < 2; ++t)
            bfr[t] = *(const bf16x8*)&Bs[(wn + t * 16 + l15) * 32 + lq * 8];
        #pragma unroll
        for (int mt = 0; mt < 4; ++mt)
            #pragma unroll
            for (int nt = 0; nt < 2; ++nt)
                acc[mt][nt] = __builtin_amdgcn_mfma_f32_16x16x32_bf16(
                    af[mt], bfr[nt], acc[mt][nt], 0, 0, 0);
        __syncthreads();
    }

    float bv[2];
    #pragma unroll
    for (int nt = 0; nt < 2; ++nt) bv[nt] = bias[bn + wn + nt * 16 + l15];
    #pragma unroll
    for (int mt = 0; mt < 4; ++mt) {
        const int row = bm + wm + mt * 16 + lq * 4;
        #pragma unroll
        for (int nt = 0; nt < 2; ++nt) {
            const int col = bn + wn + nt * 16 + l15;
            #pragma unroll
            for (int r = 0; r < 4; ++r)
                Cm[(size_t)(row + r) * N + col] = acc[mt][nt][r] + bv[nt];
        }
    }
}

// ---------------------------------------------------------------------------
extern "C" void kernel_launch(void* const* d_in, const int* in_sizes, int n_in,
                              void* d_out, int out_size, void* d_ws, size_t ws_size,
                              hipStream_t stream)
{
    const float* x      = (const float*)d_in[0];
    const float* w_qkv  = (const float*)d_in[1];
    const float* w_proj = (const float*)d_in[2];
    const float* b_proj = (const float*)d_in[3];
    float*       out    = (float*)d_out;

    // workspace: 48 MiB
    unsigned short* xb     = (unsigned short*)d_ws;                 // [4096][1024]
    unsigned short* wqkvT  = xb     + (size_t)M_ROWS * C_DIM;       // [3072][1024]
    unsigned short* wprojT = wqkvT  + (size_t)QKV_N * C_DIM;        // [1024][1024]
    unsigned short* qbuf   = wprojT + (size_t)C_DIM * C_DIM;        // [32][2048][64]
    unsigned short* kbuf   = qbuf   + (size_t)M_ROWS * C_DIM;       // [32][2048][64]
    unsigned short* vbuf   = kbuf   + (size_t)M_ROWS * C_DIM;       // [32][64][2048]
    unsigned short* attnb  = vbuf   + (size_t)M_ROWS * C_DIM;       // [4096][1024]

    // 0) fused prep (x convert + both weight transposes)
    prep_fused<<<4096 + 768 + 256, 256, 0, stream>>>(x, xb, w_qkv, wqkvT, w_proj, wprojT);

    // 1) QKV projection, region-split (branch-free K-loops)
    gemm_qkv_part<true><<<dim3(16, M_ROWS / 128), 256, 0, stream>>>(
        xb, wqkvT, qbuf, kbuf, vbuf);   // q + k
    gemm_qkv_part<false><<<dim3(8, M_ROWS / 128), 256, 0, stream>>>(
        xb, wqkvT, qbuf, kbuf, vbuf);   // v

    // 2) flash attention (double-buffered, full key sweep)
    attn_mfma<<<1024, 256, 0, stream>>>(qbuf, kbuf, vbuf, attnb);

    // 3) output projection + bias (fp32 out)
    gemm_bt<<<dim3(C_DIM / 64, M_ROWS / 128), 256, 0, stream>>>(
        attnb, wprojT, b_proj, out, M_ROWS, C_DIM, C_DIM);
}

// Round 10
// 201.346 us; speedup vs baseline: 1.0697x; 1.0697x over previous
//
#include <hip/hip_runtime.h>
#include <hip/hip_bf16.h>
#include <math.h>

// Problem constants (match reference setup_inputs)
#define B_SZ   2
#define N_SEQ  2048
#define C_DIM  1024
#define H_NUM  16
#define D_HEAD 64
#define M_ROWS (B_SZ * N_SEQ)   // 4096
#define QKV_N  (3 * C_DIM)      // 3072

typedef __attribute__((ext_vector_type(8))) short  bf16x8;
typedef __attribute__((ext_vector_type(4))) float  floatx4;

// fp32 -> bf16 bits, round-to-nearest-even
static __device__ __forceinline__ unsigned short f2bf(float x) {
    unsigned int u = __float_as_uint(x);
    u = (u + 0x7FFFu + ((u >> 16) & 1u)) >> 16;
    return (unsigned short)u;
}
// RNE-rounded bits kept in the high halfword (for pair packing via v_perm)
static __device__ __forceinline__ unsigned int f2bf_hi(float x) {
    unsigned int u = __float_as_uint(x);
    return u + 0x7FFFu + ((u >> 16) & 1u);
}
// pack (lo=a, hi=b) as two RNE bf16 in one u32
#if __has_builtin(__builtin_amdgcn_cvt_pk_bf16_f32)
typedef __bf16 bf16_2 __attribute__((ext_vector_type(2)));
static __device__ __forceinline__ unsigned int pkbf(float a, float b) {
    union { bf16_2 v; unsigned int u; } c;
    c.v = __builtin_amdgcn_cvt_pk_bf16_f32(a, b);
    return c.u;
}
#else
static __device__ __forceinline__ unsigned int pkbf(float a, float b) {
    return __builtin_amdgcn_perm(f2bf_hi(b), f2bf_hi(a), 0x07060302u);
}
#endif

#if __has_builtin(__builtin_amdgcn_exp2f)
#define EXP2F(x) __builtin_amdgcn_exp2f(x)
#else
#define EXP2F(x) exp2f(x)
#endif

#define GLP(p) ((const __attribute__((address_space(1))) void*)(p))
#define LDP(p) ((__attribute__((address_space(3))) void*)(p))

#define CEXP 0.18033688011112042f   // 0.125 * log2(e)

// ---------------------------------------------------------------------------
// Fused prep (1 launch): blocks [0,4096) convert x to bf16;
// [4096,4864) transpose-convert w_qkv; [4864,5120) transpose-convert w_proj.
// ---------------------------------------------------------------------------
__global__ __launch_bounds__(256)
void prep_fused(const float* __restrict__ x,      unsigned short* __restrict__ xb,
                const float* __restrict__ w_qkv,  unsigned short* __restrict__ wqkvT,
                const float* __restrict__ w_proj, unsigned short* __restrict__ wprojT)
{
    __shared__ unsigned short t[64][72];
    const int bid = blockIdx.x;
    const int tid = threadIdx.x;

    if (bid < 4096) {                        // x -> bf16 (exactly 1M float4 groups)
        const int i = bid * 256 + tid;
        float4 v = ((const float4*)x)[i];
        ushort4 p;
        p.x = f2bf(v.x); p.y = f2bf(v.y); p.z = f2bf(v.z); p.w = f2bf(v.w);
        ((ushort4*)xb)[i] = p;
        return;
    }

    const float* W;
    unsigned short* WT;
    int N, tt;
    if (bid < 4096 + 768) { W = w_qkv;  WT = wqkvT;  N = QKV_N; tt = bid - 4096; }
    else                  { W = w_proj; WT = wprojT; N = C_DIM; tt = bid - 4864; }
    const int ntiles = N / 64;
    const int n0 = (tt % ntiles) * 64;
    const int k0 = (tt / ntiles) * 64;
    const int K  = C_DIM;

    const int tc = tid & 15;
    const int tr = tid >> 4;
    #pragma unroll
    for (int p = 0; p < 4; ++p) {
        const int r = tr + p * 16;
        float4 v = *(const float4*)&W[(size_t)(k0 + r) * N + n0 + tc * 4];
        ushort4 pk;
        pk.x = f2bf(v.x); pk.y = f2bf(v.y); pk.z = f2bf(v.z); pk.w = f2bf(v.w);
        *(ushort4*)&t[r][tc * 4] = pk;
    }
    __syncthreads();

    const int n  = tid >> 2;
    const int c0 = (tid & 3) * 16;
    unsigned short tmp[16];
    #pragma unroll
    for (int i = 0; i < 16; ++i) tmp[i] = t[c0 + i][n];
    *(uint4*)&WT[(size_t)(n0 + n) * K + k0 + c0]     = *(uint4*)&tmp[0];
    *(uint4*)&WT[(size_t)(n0 + n) * K + k0 + c0 + 8] = *(uint4*)&tmp[8];
}

// ---------------------------------------------------------------------------
// QKV GEMM (m97 structure) with routing epilogue — R6 measured-best form:
// single kernel, normal MFMA order, region branch only in the epilogue.
//   qkv[row][col] -> qbuf[(b,h)][n][d] (q PRE-SCALED by CEXP),
//                    kbuf[(b,h)][n][d],
//                    vbuf[(b,h)][d][n'] (transposed, keys permuted per-64:
//                    n' = (n&~63)|fk, fk = (a&0x20)|((a&0x0C)<<1)|((a&0x10)>>2)|(a&3))
// ---------------------------------------------------------------------------
__global__ __launch_bounds__(256)
void gemm_qkv(const unsigned short* __restrict__ A,   // xb [4096][1024]
              const unsigned short* __restrict__ BT,  // wqkvT [3072][1024]
              unsigned short* __restrict__ qbuf,
              unsigned short* __restrict__ kbuf,
              unsigned short* __restrict__ vbuf)
{
    const int K = C_DIM;
    __shared__ unsigned short As[128 * 32];
    __shared__ unsigned short Bs[128 * 32];

    const int tid  = threadIdx.x;
    const int lane = tid & 63;
    const int wave = tid >> 6;
    const int l15  = lane & 15;
    const int lq   = lane >> 4;
    const int wm   = (wave & 1) * 64;
    const int wn   = (wave >> 1) * 64;

    const int bm = blockIdx.y * 128;
    const int bn = blockIdx.x * 128;

    const int sr = tid >> 2;
    const int sc = (tid & 3) * 8;

    const unsigned short* ga0 = A  + (size_t)(bm + sr) * K + sc;
    const unsigned short* ga1 = A  + (size_t)(bm + 64 + sr) * K + sc;
    const unsigned short* gb0 = BT + (size_t)(bn + sr) * K + sc;
    const unsigned short* gb1 = BT + (size_t)(bn + 64 + sr) * K + sc;

    unsigned short* la0 = &As[sr * 32 + sc];
    unsigned short* la1 = &As[(64 + sr) * 32 + sc];
    unsigned short* lb0 = &Bs[sr * 32 + sc];
    unsigned short* lb1 = &Bs[(64 + sr) * 32 + sc];

    floatx4 acc[4][4];
    #pragma unroll
    for (int i = 0; i < 4; ++i)
        #pragma unroll
        for (int j = 0; j < 4; ++j) acc[i][j] = (floatx4){0.f, 0.f, 0.f, 0.f};

    for (int kt = 0; kt < K; kt += 32) {
        __builtin_amdgcn_global_load_lds(GLP(ga0), LDP(la0), 16, 0, 0);
        __builtin_amdgcn_global_load_lds(GLP(ga1), LDP(la1), 16, 0, 0);
        __builtin_amdgcn_global_load_lds(GLP(gb0), LDP(lb0), 16, 0, 0);
        __builtin_amdgcn_global_load_lds(GLP(gb1), LDP(lb1), 16, 0, 0);
        ga0 += 32; ga1 += 32; gb0 += 32; gb1 += 32;
        __syncthreads();

        bf16x8 af[4], bfr[4];
        #pragma unroll
        for (int t = 0; t < 4; ++t) {
            af[t]  = *(const bf16x8*)&As[(wm + t * 16 + l15) * 32 + lq * 8];
            bfr[t] = *(const bf16x8*)&Bs[(wn + t * 16 + l15) * 32 + lq * 8];
        }
        #pragma unroll
        for (int mt = 0; mt < 4; ++mt)
            #pragma unroll
            for (int nt = 0; nt < 4; ++nt)
                acc[mt][nt] = __builtin_amdgcn_mfma_f32_16x16x32_bf16(
                    af[mt], bfr[nt], acc[mt][nt], 0, 0, 0);
        __syncthreads();
    }

    // routing epilogue (regions are 1024-col aligned; 16-col groups head-uniform)
    #pragma unroll
    for (int nt = 0; nt < 4; ++nt) {
        const int col  = bn + wn + nt * 16 + l15;
        const int reg3 = col >> 10;            // 0=q, 1=k, 2=v
        const int h    = (col >> 6) & 15;
        const int d    = col & 63;
        const float sc4 = (reg3 == 0) ? CEXP : 1.0f;   // fold softmax scale into q
        #pragma unroll
        for (int mt = 0; mt < 4; ++mt) {
            const int row = bm + wm + mt * 16 + lq * 4;   // multiple of 4
            const int b   = row >> 11;
            const int n   = row & 2047;
            if (reg3 < 2) {
                unsigned short* dst = (reg3 ? kbuf : qbuf)
                    + ((size_t)(b * H_NUM + h) * N_SEQ + n) * D_HEAD + d;
                #pragma unroll
                for (int r = 0; r < 4; ++r)
                    dst[(size_t)r * D_HEAD] = f2bf(acc[mt][nt][r] * sc4);
            } else {
                const int a  = n & 63;   // low 2 bits zero
                const int fk = (a & 0x20) | ((a & 0x0C) << 1) | ((a & 0x10) >> 2);
                unsigned short* dst = vbuf
                    + ((size_t)(b * H_NUM + h) * D_HEAD + d) * N_SEQ + (n & ~63) + fk;
                ushort4 pk;
                pk.x = f2bf(acc[mt][nt][0]); pk.y = f2bf(acc[mt][nt][1]);
                pk.z = f2bf(acc[mt][nt][2]); pk.w = f2bf(acc[mt][nt][3]);
                *(ushort4*)dst = pk;
            }
        }
    }
}

// ---------------------------------------------------------------------------
// S^T-form bf16 MFMA flash attention, fixed-max softmax.
// Block = 8 waves (512 threads); wave = 16 q-rows; grid = 512 blocks
// (2 blocks/CU, 16 waves/CU). 64-key double-buffered LDS tiles via
// global_load_lds with XOR segment swizzle; 8 waves share each tile.
// q pre-scaled by CEXP; S-acc init -8 folds the softmax shift.
// ---------------------------------------------------------------------------
__global__ __launch_bounds__(512)
void attn_mfma(const unsigned short* __restrict__ qbuf,
               const unsigned short* __restrict__ kbuf,
               const unsigned short* __restrict__ vbuf,
               unsigned short* __restrict__ attnb)
{
    __shared__ unsigned short KsS[2][64 * 64];
    __shared__ unsigned short VtS[2][64 * 64];

    const int tid  = threadIdx.x;
    const int lane = tid & 63;
    const int wave = tid >> 6;           // 0..7
    const int l15  = lane & 15;
    const int lq   = lane >> 4;
    const int e    = l15 & 7;

    // XCD swizzle: low 3 bits pick XCD; same bh stays in one XCD group
    const int bid  = blockIdx.x;                    // 0..511
    const int bh   = (bid & 7) * 4 + (bid >> 7);    // 0..31
    const int qblk = (bid >> 3) & 15;               // 0..15
    const int b    = bh >> 4;
    const int h    = bh & 15;
    const int q0   = qblk * 128 + wave * 16;

    const unsigned short* khead = kbuf + (size_t)bh * N_SEQ * D_HEAD;
    const unsigned short* vhead = vbuf + (size_t)bh * D_HEAD * N_SEQ;

    // Q B-frags (q pre-scaled by CEXP at gemm_qkv)
    bf16x8 qf[2];
    {
        const unsigned short* qrow = qbuf
            + ((size_t)bh * N_SEQ + q0 + l15) * D_HEAD + lq * 8;
        qf[0] = *(const bf16x8*)qrow;
        qf[1] = *(const bf16x8*)(qrow + 32);
    }

    floatx4 acc[4];
    #pragma unroll
    for (int dc = 0; dc < 4; ++dc) acc[dc] = (floatx4){0.f, 0.f, 0.f, 0.f};
    float lsum = 0.f;

    // staging: 512 threads x 16B = one full 8KB tile per issue.
    // row = tid>>3 (0..63), seg = tid&7, global seg = seg^(row&7)
    const int srow = tid >> 3;
    const int gso  = ((tid & 7) ^ (srow & 7)) * 8;

    // prologue: stage tile 0 into buffer 0 (K then V, one issue each)
    __builtin_amdgcn_global_load_lds(GLP(khead + (size_t)srow * 64 + gso),
                                     LDP(&KsS[0][tid * 8]), 16, 0, 0);
    __builtin_amdgcn_global_load_lds(GLP(vhead + (size_t)srow * N_SEQ + gso),
                                     LDP(&VtS[0][tid * 8]), 16, 0, 0);

    for (int tile = 0; tile < N_SEQ / 64; ++tile) {
        const int cur = tile & 1;
        __syncthreads();   // drains DMA for cur; prior reads of cur^1 done

        if (tile + 1 < N_SEQ / 64) {
            const int m1 = (tile + 1) * 64;
            const int nx = cur ^ 1;
            __builtin_amdgcn_global_load_lds(GLP(khead + (size_t)(m1 + srow) * 64 + gso),
                                             LDP(&KsS[nx][tid * 8]), 16, 0, 0);
            __builtin_amdgcn_global_load_lds(GLP(vhead + (size_t)srow * N_SEQ + m1 + gso),
                                             LDP(&VtS[nx][tid * 8]), 16, 0, 0);
        }

        const unsigned short* Ksc = &KsS[cur][0];
        const unsigned short* Vtc = &VtS[cur][0];

        // S^T = K Q^T (acc init -8 folds the softmax shift)
        floatx4 st[4];
        #pragma unroll
        for (int t = 0; t < 4; ++t) {
            bf16x8 k0 = *(const bf16x8*)&Ksc[(t * 16 + l15) * 64 + ((lq ^ e) * 8)];
            bf16x8 k1 = *(const bf16x8*)&Ksc[(t * 16 + l15) * 64 + (((4 + lq) ^ e) * 8)];
            floatx4 s = (floatx4){-8.f, -8.f, -8.f, -8.f};
            s = __builtin_amdgcn_mfma_f32_16x16x32_bf16(k0, qf[0], s, 0, 0, 0);
            s = __builtin_amdgcn_mfma_f32_16x16x32_bf16(k1, qf[1], s, 0, 0, 0);
            st[t] = s;
        }

        // fixed-max softmax: p = 2^st; packed RNE bf16 pairs
        unsigned int pk[8];
        float la = 0.f;
        #pragma unroll
        for (int t = 0; t < 4; ++t) {
            float p0 = EXP2F(st[t][0]);
            float p1 = EXP2F(st[t][1]);
            float p2 = EXP2F(st[t][2]);
            float p3 = EXP2F(st[t][3]);
            la += (p0 + p1) + (p2 + p3);
            pk[t * 2]     = pkbf(p0, p1);
            pk[t * 2 + 1] = pkbf(p2, p3);
        }
        lsum += la;
        union { uint4 u; bf16x8 v; } cvt0, cvt1;
        cvt0.u = make_uint4(pk[0], pk[1], pk[2], pk[3]);
        cvt1.u = make_uint4(pk[4], pk[5], pk[6], pk[7]);

        // O^T += V^T P^T (keys permuted consistently via vbuf layout)
        #pragma unroll
        for (int dc = 0; dc < 4; ++dc) {
            bf16x8 v0 = *(const bf16x8*)&Vtc[(dc * 16 + l15) * 64 + ((lq ^ e) * 8)];
            bf16x8 v1 = *(const bf16x8*)&Vtc[(dc * 16 + l15) * 64 + (((4 + lq) ^ e) * 8)];
            acc[dc] = __builtin_amdgcn_mfma_f32_16x16x32_bf16(v0, cvt0.v, acc[dc], 0, 0, 0);
            acc[dc] = __builtin_amdgcn_mfma_f32_16x16x32_bf16(v1, cvt1.v, acc[dc], 0, 0, 0);
        }
    }

    // epilogue: reduce l across lq groups, normalize, store bf16
    float l = lsum;
    l += __shfl_xor(l, 16, 64);
    l += __shfl_xor(l, 32, 64);
    const float inv = 1.f / l;
    const int q = q0 + l15;
    unsigned short* orow = attnb + ((size_t)b * N_SEQ + q) * C_DIM + h * D_HEAD;
    #pragma unroll
    for (int dc = 0; dc < 4; ++dc) {
        ushort4 pkk;
        pkk.x = f2bf(acc[dc][0] * inv);
        pkk.y = f2bf(acc[dc][1] * inv);
        pkk.z = f2bf(acc[dc][2] * inv);
        pkk.w = f2bf(acc[dc][3] * inv);
        *(ushort4*)&orow[dc * 16 + lq * 4] = pkk;
    }
}

// ---------------------------------------------------------------------------
// bf16 GEMM for the output projection: 128(M) x 64(N) tile, BK=32.
// Grid (N/64, M/128) = 512 blocks -> 2 blocks/CU.
// ---------------------------------------------------------------------------
__global__ __launch_bounds__(256)
void gemm_bt(const unsigned short* __restrict__ A,   // [M][K] bf16
             const unsigned short* __restrict__ BT,  // [N][K] bf16
             const float* __restrict__ bias,         // [N] fp32
             float* __restrict__ Cm,
             int M, int N, int K)
{
    __shared__ unsigned short As[128 * 32];
    __shared__ unsigned short Bs[64 * 32];

    const int tid  = threadIdx.x;
    const int lane = tid & 63;
    const int wave = tid >> 6;
    const int l15  = lane & 15;
    const int lq   = lane >> 4;
    const int wm   = (wave & 1) * 64;
    const int wn   = (wave >> 1) * 32;

    const int bm = blockIdx.y * 128;
    const int bn = blockIdx.x * 64;

    const int sr = tid >> 2;
    const int sc = (tid & 3) * 8;

    const unsigned short* ga0 = A  + (size_t)(bm + sr) * K + sc;
    const unsigned short* ga1 = A  + (size_t)(bm + 64 + sr) * K + sc;
    const unsigned short* gb0 = BT + (size_t)(bn + sr) * K + sc;

    unsigned short* la0 = &As[sr * 32 + sc];
    unsigned short* la1 = &As[(64 + sr) * 32 + sc];
    unsigned short* lb0 = &Bs[sr * 32 + sc];

    floatx4 acc[4][2];
    #pragma unroll
    for (int i = 0; i < 4; ++i)
        #pragma unroll
        for (int j = 0; j < 2; ++j) acc[i][j] = (floatx4){0.f, 0.f, 0.f, 0.f};

    for (int kt = 0; kt < K; kt += 32) {
        __builtin_amdgcn_global_load_lds(GLP(ga0), LDP(la0), 16, 0, 0);
        __builtin_amdgcn_global_load_lds(GLP(ga1), LDP(la1), 16, 0, 0);
        __builtin_amdgcn_global_load_lds(GLP(gb0), LDP(lb0), 16, 0, 0);
        ga0 += 32; ga1 += 32; gb0 += 32;
        __syncthreads();

        bf16x8 af[4], bfr[2];
        #pragma unroll
        for (int t = 0; t < 4; ++t)
            af[t] = *(const bf16x8*)&As[(wm + t * 16 + l15) * 32 + lq * 8];
        #pragma unroll
        for (int t = 0; t < 2; ++t)
            bfr[t] = *(const bf16x8*)&Bs[(wn + t * 16 + l15) * 32 + lq * 8];
        #pragma unroll
        for (int mt = 0; mt < 4; ++mt)
            #pragma unroll
            for (int nt = 0; nt < 2; ++nt)
                acc[mt][nt] = __builtin_amdgcn_mfma_f32_16x16x32_bf16(
                    af[mt], bfr[nt], acc[mt][nt], 0, 0, 0);
        __syncthreads();
    }

    float bv[2];
    #pragma unroll
    for (int nt = 0; nt < 2; ++nt) bv[nt] = bias[bn + wn + nt * 16 + l15];
    #pragma unroll
    for (int mt = 0; mt < 4; ++mt) {
        const int row = bm + wm + mt * 16 + lq * 4;
        #pragma unroll
        for (int nt = 0; nt < 2; ++nt) {
            const int col = bn + wn + nt * 16 + l15;
            #pragma unroll
            for (int r = 0; r < 4; ++r)
                Cm[(size_t)(row + r) * N + col] = acc[mt][nt][r] + bv[nt];
        }
    }
}

// ---------------------------------------------------------------------------
extern "C" void kernel_launch(void* const* d_in, const int* in_sizes, int n_in,
                              void* d_out, int out_size, void* d_ws, size_t ws_size,
                              hipStream_t stream)
{
    const float* x      = (const float*)d_in[0];
    const float* w_qkv  = (const float*)d_in[1];
    const float* w_proj = (const float*)d_in[2];
    const float* b_proj = (const float*)d_in[3];
    float*       out    = (float*)d_out;

    // workspace: 48 MiB
    unsigned short* xb     = (unsigned short*)d_ws;                 // [4096][1024]
    unsigned short* wqkvT  = xb     + (size_t)M_ROWS * C_DIM;       // [3072][1024]
    unsigned short* wprojT = wqkvT  + (size_t)QKV_N * C_DIM;        // [1024][1024]
    unsigned short* qbuf   = wprojT + (size_t)C_DIM * C_DIM;        // [32][2048][64]
    unsigned short* kbuf   = qbuf   + (size_t)M_ROWS * C_DIM;       // [32][2048][64]
    unsigned short* vbuf   = kbuf   + (size_t)M_ROWS * C_DIM;       // [32][64][2048]
    unsigned short* attnb  = vbuf   + (size_t)M_ROWS * C_DIM;       // [4096][1024]

    // 0) fused prep (x convert + both weight transposes)
    prep_fused<<<4096 + 768 + 256, 256, 0, stream>>>(x, xb, w_qkv, wqkvT, w_proj, wprojT);

    // 1) QKV projection with routing epilogue (single kernel, R6 form)
    gemm_qkv<<<dim3(QKV_N / 128, M_ROWS / 128), 256, 0, stream>>>(xb, wqkvT, qbuf, kbuf, vbuf);

    // 2) flash attention (8 waves/block, 512 blocks, double-buffered)
    attn_mfma<<<512, 512, 0, stream>>>(qbuf, kbuf, vbuf, attnb);

    // 3) output projection + bias (fp32 out)
    gemm_bt<<<dim3(C_DIM / 64, M_ROWS / 128), 256, 0, stream>>>(
        attnb, wprojT, b_proj, out, M_ROWS, C_DIM, C_DIM);
}

// Round 11
// 191.066 us; speedup vs baseline: 1.1273x; 1.0538x over previous
//
#include <hip/hip_runtime.h>
#include <hip/hip_bf16.h>
#include <math.h>

// Problem constants (match reference setup_inputs)
#define B_SZ   2
#define N_SEQ  2048
#define C_DIM  1024
#define H_NUM  16
#define D_HEAD 64
#define M_ROWS (B_SZ * N_SEQ)   // 4096
#define QKV_N  (3 * C_DIM)      // 3072

typedef __attribute__((ext_vector_type(8))) short  bf16x8;
typedef __attribute__((ext_vector_type(4))) float  floatx4;

// fp32 -> bf16 bits, round-to-nearest-even
static __device__ __forceinline__ unsigned short f2bf(float x) {
    unsigned int u = __float_as_uint(x);
    u = (u + 0x7FFFu + ((u >> 16) & 1u)) >> 16;
    return (unsigned short)u;
}
// RNE-rounded bits kept in the high halfword (for pair packing via v_perm)
static __device__ __forceinline__ unsigned int f2bf_hi(float x) {
    unsigned int u = __float_as_uint(x);
    return u + 0x7FFFu + ((u >> 16) & 1u);
}
// pack (lo=a, hi=b) as two RNE bf16 in one u32
#if __has_builtin(__builtin_amdgcn_cvt_pk_bf16_f32)
typedef __bf16 bf16_2 __attribute__((ext_vector_type(2)));
static __device__ __forceinline__ unsigned int pkbf(float a, float b) {
    union { bf16_2 v; unsigned int u; } c;
    c.v = __builtin_amdgcn_cvt_pk_bf16_f32(a, b);
    return c.u;
}
#else
static __device__ __forceinline__ unsigned int pkbf(float a, float b) {
    return __builtin_amdgcn_perm(f2bf_hi(b), f2bf_hi(a), 0x07060302u);
}
#endif

#if __has_builtin(__builtin_amdgcn_exp2f)
#define EXP2F(x) __builtin_amdgcn_exp2f(x)
#else
#define EXP2F(x) exp2f(x)
#endif

#define GLP(p) ((const __attribute__((address_space(1))) void*)(p))
#define LDP(p) ((__attribute__((address_space(3))) void*)(p))

#define CEXP 0.18033688011112042f   // 0.125 * log2(e)

// ---------------------------------------------------------------------------
// Fused prep (1 launch): blocks [0,4096) convert x to bf16;
// [4096,4864) transpose-convert w_qkv; [4864,5120) transpose-convert w_proj.
// ---------------------------------------------------------------------------
__global__ __launch_bounds__(256)
void prep_fused(const float* __restrict__ x,      unsigned short* __restrict__ xb,
                const float* __restrict__ w_qkv,  unsigned short* __restrict__ wqkvT,
                const float* __restrict__ w_proj, unsigned short* __restrict__ wprojT)
{
    __shared__ unsigned short t[64][72];
    const int bid = blockIdx.x;
    const int tid = threadIdx.x;

    if (bid < 4096) {                        // x -> bf16 (exactly 1M float4 groups)
        const int i = bid * 256 + tid;
        float4 v = ((const float4*)x)[i];
        ushort4 p;
        p.x = f2bf(v.x); p.y = f2bf(v.y); p.z = f2bf(v.z); p.w = f2bf(v.w);
        ((ushort4*)xb)[i] = p;
        return;
    }

    const float* W;
    unsigned short* WT;
    int N, tt;
    if (bid < 4096 + 768) { W = w_qkv;  WT = wqkvT;  N = QKV_N; tt = bid - 4096; }
    else                  { W = w_proj; WT = wprojT; N = C_DIM; tt = bid - 4864; }
    const int ntiles = N / 64;
    const int n0 = (tt % ntiles) * 64;
    const int k0 = (tt / ntiles) * 64;
    const int K  = C_DIM;

    const int tc = tid & 15;
    const int tr = tid >> 4;
    #pragma unroll
    for (int p = 0; p < 4; ++p) {
        const int r = tr + p * 16;
        float4 v = *(const float4*)&W[(size_t)(k0 + r) * N + n0 + tc * 4];
        ushort4 pk;
        pk.x = f2bf(v.x); pk.y = f2bf(v.y); pk.z = f2bf(v.z); pk.w = f2bf(v.w);
        *(ushort4*)&t[r][tc * 4] = pk;
    }
    __syncthreads();

    const int n  = tid >> 2;
    const int c0 = (tid & 3) * 16;
    unsigned short tmp[16];
    #pragma unroll
    for (int i = 0; i < 16; ++i) tmp[i] = t[c0 + i][n];
    *(uint4*)&WT[(size_t)(n0 + n) * K + k0 + c0]     = *(uint4*)&tmp[0];
    *(uint4*)&WT[(size_t)(n0 + n) * K + k0 + c0 + 8] = *(uint4*)&tmp[8];
}

// ---------------------------------------------------------------------------
// QKV GEMM, BK=64 + XOR-swizzled LDS (conflict-free ds_read_b128, attn recipe)
// + XCD-grouped grid swizzle. Routing epilogue unchanged (R6 measured-best):
//   qbuf[(b,h)][n][d] (q PRE-SCALED by CEXP), kbuf[(b,h)][n][d],
//   vbuf[(b,h)][d][n'] (transposed, keys permuted per-64:
//   n' = (n&~63)|fk, fk = (a&0x20)|((a&0x0C)<<1)|((a&0x10)>>2)|(a&3))
// LDS physical: row-major 64-elem rows; seg s of row r holds logical cols
// ((s^(r&7))*8..+8). Staged via glds (dst = base + tid*16B); gso issue-
// invariant because 32 = 0 mod 8.
// ---------------------------------------------------------------------------
__global__ __launch_bounds__(256)
void gemm_qkv(const unsigned short* __restrict__ A,   // xb [4096][1024]
              const unsigned short* __restrict__ BT,  // wqkvT [3072][1024]
              unsigned short* __restrict__ qbuf,
              unsigned short* __restrict__ kbuf,
              unsigned short* __restrict__ vbuf)
{
    const int K = C_DIM;
    __shared__ unsigned short As[128 * 64];   // 16 KB
    __shared__ unsigned short Bs[128 * 64];   // 16 KB

    const int tid  = threadIdx.x;
    const int lane = tid & 63;
    const int wave = tid >> 6;
    const int l15  = lane & 15;
    const int lq   = lane >> 4;
    const int e7   = l15 & 7;
    const int wm   = (wave & 1) * 64;
    const int wn   = (wave >> 1) * 64;

    // XCD-grouped swizzle: xcd = bid&7; same-bm blocks consecutive per XCD.
    const int bid = blockIdx.x;             // 0..767
    const int xcd = bid & 7;
    const int j   = bid >> 3;               // 0..95
    const int bm  = (j / 3) * 128;
    const int bn  = ((j % 3) * 8 + xcd) * 128;

    // staging: 4 issues per buffer; issue i rows i*32+srow, phys seg = tid&7
    const int srow = tid >> 3;              // 0..31
    const int gso  = ((tid & 7) ^ (srow & 7)) * 8;   // logical col chunk

    const unsigned short* ga = A  + (size_t)(bm + srow) * K + gso;
    const unsigned short* gb = BT + (size_t)(bn + srow) * K + gso;

    floatx4 acc[4][4];
    #pragma unroll
    for (int i = 0; i < 4; ++i)
        #pragma unroll
        for (int jj = 0; jj < 4; ++jj) acc[i][jj] = (floatx4){0.f, 0.f, 0.f, 0.f};

    for (int kt = 0; kt < K; kt += 64) {
        #pragma unroll
        for (int i = 0; i < 4; ++i) {
            __builtin_amdgcn_global_load_lds(GLP(ga + (size_t)i * 32 * K + kt),
                                             LDP(&As[i * 2048 + tid * 8]), 16, 0, 0);
            __builtin_amdgcn_global_load_lds(GLP(gb + (size_t)i * 32 * K + kt),
                                             LDP(&Bs[i * 2048 + tid * 8]), 16, 0, 0);
        }
        __syncthreads();

        bf16x8 af[2][4], bfr[2][4];
        #pragma unroll
        for (int t = 0; t < 4; ++t) {
            #pragma unroll
            for (int kc = 0; kc < 2; ++kc) {
                af[kc][t]  = *(const bf16x8*)&As[(wm + t * 16 + l15) * 64
                                                 + (((kc * 4 + lq) ^ e7) * 8)];
                bfr[kc][t] = *(const bf16x8*)&Bs[(wn + t * 16 + l15) * 64
                                                 + (((kc * 4 + lq) ^ e7) * 8)];
            }
        }
        #pragma unroll
        for (int kc = 0; kc < 2; ++kc)
            #pragma unroll
            for (int mt = 0; mt < 4; ++mt)
                #pragma unroll
                for (int nt = 0; nt < 4; ++nt)
                    acc[mt][nt] = __builtin_amdgcn_mfma_f32_16x16x32_bf16(
                        af[kc][mt], bfr[kc][nt], acc[mt][nt], 0, 0, 0);
        __syncthreads();
    }

    // routing epilogue (regions are 1024-col aligned; 16-col groups head-uniform)
    #pragma unroll
    for (int nt = 0; nt < 4; ++nt) {
        const int col  = bn + wn + nt * 16 + l15;
        const int reg3 = col >> 10;            // 0=q, 1=k, 2=v
        const int h    = (col >> 6) & 15;
        const int d    = col & 63;
        const float sc4 = (reg3 == 0) ? CEXP : 1.0f;   // fold softmax scale into q
        #pragma unroll
        for (int mt = 0; mt < 4; ++mt) {
            const int row = bm + wm + mt * 16 + lq * 4;   // multiple of 4
            const int b   = row >> 11;
            const int n   = row & 2047;
            if (reg3 < 2) {
                unsigned short* dst = (reg3 ? kbuf : qbuf)
                    + ((size_t)(b * H_NUM + h) * N_SEQ + n) * D_HEAD + d;
                #pragma unroll
                for (int r = 0; r < 4; ++r)
                    dst[(size_t)r * D_HEAD] = f2bf(acc[mt][nt][r] * sc4);
            } else {
                const int a  = n & 63;   // low 2 bits zero
                const int fk = (a & 0x20) | ((a & 0x0C) << 1) | ((a & 0x10) >> 2);
                unsigned short* dst = vbuf
                    + ((size_t)(b * H_NUM + h) * D_HEAD + d) * N_SEQ + (n & ~63) + fk;
                ushort4 pk;
                pk.x = f2bf(acc[mt][nt][0]); pk.y = f2bf(acc[mt][nt][1]);
                pk.z = f2bf(acc[mt][nt][2]); pk.w = f2bf(acc[mt][nt][3]);
                *(ushort4*)dst = pk;
            }
        }
    }
}

// ---------------------------------------------------------------------------
// S^T-form bf16 MFMA flash attention, fixed-max softmax.
// Block = 8 waves (512 threads); wave = 16 q-rows; grid = 512 blocks
// (2 blocks/CU, 16 waves/CU). 64-key double-buffered LDS tiles via
// global_load_lds with XOR segment swizzle; 8 waves share each tile.
// q pre-scaled by CEXP; S-acc init -8 folds the softmax shift.
// ---------------------------------------------------------------------------
__global__ __launch_bounds__(512)
void attn_mfma(const unsigned short* __restrict__ qbuf,
               const unsigned short* __restrict__ kbuf,
               const unsigned short* __restrict__ vbuf,
               unsigned short* __restrict__ attnb)
{
    __shared__ unsigned short KsS[2][64 * 64];
    __shared__ unsigned short VtS[2][64 * 64];

    const int tid  = threadIdx.x;
    const int lane = tid & 63;
    const int wave = tid >> 6;           // 0..7
    const int l15  = lane & 15;
    const int lq   = lane >> 4;
    const int e    = l15 & 7;

    // XCD swizzle: low 3 bits pick XCD; same bh stays in one XCD group
    const int bid  = blockIdx.x;                    // 0..511
    const int bh   = (bid & 7) * 4 + (bid >> 7);    // 0..31
    const int qblk = (bid >> 3) & 15;               // 0..15
    const int b    = bh >> 4;
    const int h    = bh & 15;
    const int q0   = qblk * 128 + wave * 16;

    const unsigned short* khead = kbuf + (size_t)bh * N_SEQ * D_HEAD;
    const unsigned short* vhead = vbuf + (size_t)bh * D_HEAD * N_SEQ;

    // Q B-frags (q pre-scaled by CEXP at gemm_qkv)
    bf16x8 qf[2];
    {
        const unsigned short* qrow = qbuf
            + ((size_t)bh * N_SEQ + q0 + l15) * D_HEAD + lq * 8;
        qf[0] = *(const bf16x8*)qrow;
        qf[1] = *(const bf16x8*)(qrow + 32);
    }

    floatx4 acc[4];
    #pragma unroll
    for (int dc = 0; dc < 4; ++dc) acc[dc] = (floatx4){0.f, 0.f, 0.f, 0.f};
    float lsum = 0.f;

    // staging: 512 threads x 16B = one full 8KB tile per issue.
    // row = tid>>3 (0..63), seg = tid&7, global seg = seg^(row&7)
    const int srow = tid >> 3;
    const int gso  = ((tid & 7) ^ (srow & 7)) * 8;

    // prologue: stage tile 0 into buffer 0 (K then V, one issue each)
    __builtin_amdgcn_global_load_lds(GLP(khead + (size_t)srow * 64 + gso),
                                     LDP(&KsS[0][tid * 8]), 16, 0, 0);
    __builtin_amdgcn_global_load_lds(GLP(vhead + (size_t)srow * N_SEQ + gso),
                                     LDP(&VtS[0][tid * 8]), 16, 0, 0);

    for (int tile = 0; tile < N_SEQ / 64; ++tile) {
        const int cur = tile & 1;
        __syncthreads();   // drains DMA for cur; prior reads of cur^1 done

        if (tile + 1 < N_SEQ / 64) {
            const int m1 = (tile + 1) * 64;
            const int nx = cur ^ 1;
            __builtin_amdgcn_global_load_lds(GLP(khead + (size_t)(m1 + srow) * 64 + gso),
                                             LDP(&KsS[nx][tid * 8]), 16, 0, 0);
            __builtin_amdgcn_global_load_lds(GLP(vhead + (size_t)srow * N_SEQ + m1 + gso),
                                             LDP(&VtS[nx][tid * 8]), 16, 0, 0);
        }

        const unsigned short* Ksc = &KsS[cur][0];
        const unsigned short* Vtc = &VtS[cur][0];

        // S^T = K Q^T (acc init -8 folds the softmax shift)
        floatx4 st[4];
        #pragma unroll
        for (int t = 0; t < 4; ++t) {
            bf16x8 k0 = *(const bf16x8*)&Ksc[(t * 16 + l15) * 64 + ((lq ^ e) * 8)];
            bf16x8 k1 = *(const bf16x8*)&Ksc[(t * 16 + l15) * 64 + (((4 + lq) ^ e) * 8)];
            floatx4 s = (floatx4){-8.f, -8.f, -8.f, -8.f};
            s = __builtin_amdgcn_mfma_f32_16x16x32_bf16(k0, qf[0], s, 0, 0, 0);
            s = __builtin_amdgcn_mfma_f32_16x16x32_bf16(k1, qf[1], s, 0, 0, 0);
            st[t] = s;
        }

        // fixed-max softmax: p = 2^st; packed RNE bf16 pairs
        unsigned int pk[8];
        float la = 0.f;
        #pragma unroll
        for (int t = 0; t < 4; ++t) {
            float p0 = EXP2F(st[t][0]);
            float p1 = EXP2F(st[t][1]);
            float p2 = EXP2F(st[t][2]);
            float p3 = EXP2F(st[t][3]);
            la += (p0 + p1) + (p2 + p3);
            pk[t * 2]     = pkbf(p0, p1);
            pk[t * 2 + 1] = pkbf(p2, p3);
        }
        lsum += la;
        union { uint4 u; bf16x8 v; } cvt0, cvt1;
        cvt0.u = make_uint4(pk[0], pk[1], pk[2], pk[3]);
        cvt1.u = make_uint4(pk[4], pk[5], pk[6], pk[7]);

        // O^T += V^T P^T (keys permuted consistently via vbuf layout)
        #pragma unroll
        for (int dc = 0; dc < 4; ++dc) {
            bf16x8 v0 = *(const bf16x8*)&Vtc[(dc * 16 + l15) * 64 + ((lq ^ e) * 8)];
            bf16x8 v1 = *(const bf16x8*)&Vtc[(dc * 16 + l15) * 64 + (((4 + lq) ^ e) * 8)];
            acc[dc] = __builtin_amdgcn_mfma_f32_16x16x32_bf16(v0, cvt0.v, acc[dc], 0, 0, 0);
            acc[dc] = __builtin_amdgcn_mfma_f32_16x16x32_bf16(v1, cvt1.v, acc[dc], 0, 0, 0);
        }
    }

    // epilogue: reduce l across lq groups, normalize, store bf16
    float l = lsum;
    l += __shfl_xor(l, 16, 64);
    l += __shfl_xor(l, 32, 64);
    const float inv = 1.f / l;
    const int q = q0 + l15;
    unsigned short* orow = attnb + ((size_t)b * N_SEQ + q) * C_DIM + h * D_HEAD;
    #pragma unroll
    for (int dc = 0; dc < 4; ++dc) {
        ushort4 pkk;
        pkk.x = f2bf(acc[dc][0] * inv);
        pkk.y = f2bf(acc[dc][1] * inv);
        pkk.z = f2bf(acc[dc][2] * inv);
        pkk.w = f2bf(acc[dc][3] * inv);
        *(ushort4*)&orow[dc * 16 + lq * 4] = pkk;
    }
}

// ---------------------------------------------------------------------------
// Output projection GEMM: 128(M) x 64(N) tile, BK=64 + XOR-swizzled LDS
// (conflict-free), XCD-grouped grid swizzle. fp32 out + bias.
// ---------------------------------------------------------------------------
__global__ __launch_bounds__(256)
void gemm_bt(const unsigned short* __restrict__ A,   // [M][K] bf16
             const unsigned short* __restrict__ BT,  // [N][K] bf16
             const float* __restrict__ bias,         // [N] fp32
             float* __restrict__ Cm,
             int M, int N, int K)
{
    __shared__ unsigned short As[128 * 64];   // 16 KB
    __shared__ unsigned short Bs[64 * 64];    // 8 KB

    const int tid  = threadIdx.x;
    const int lane = tid & 63;
    const int wave = tid >> 6;
    const int l15  = lane & 15;
    const int lq   = lane >> 4;
    const int e7   = l15 & 7;
    const int wm   = (wave & 1) * 64;
    const int wn   = (wave >> 1) * 32;

    // swizzle: xcd = bid&7; bn = (j&1)*8+xcd tile, bm = j>>1
    const int bid = blockIdx.x;             // 0..511
    const int xcd = bid & 7;
    const int j   = bid >> 3;               // 0..63
    const int bm  = (j >> 1) * 128;
    const int bn  = ((j & 1) * 8 + xcd) * 64;

    const int srow = tid >> 3;              // 0..31
    const int gso  = ((tid & 7) ^ (srow & 7)) * 8;

    const unsigned short* ga = A  + (size_t)(bm + srow) * K + gso;
    const unsigned short* gb = BT + (size_t)(bn + srow) * K + gso;

    floatx4 acc[4][2];
    #pragma unroll
    for (int i = 0; i < 4; ++i)
        #pragma unroll
        for (int jj = 0; jj < 2; ++jj) acc[i][jj] = (floatx4){0.f, 0.f, 0.f, 0.f};

    for (int kt = 0; kt < K; kt += 64) {
        #pragma unroll
        for (int i = 0; i < 4; ++i)
            __builtin_amdgcn_global_load_lds(GLP(ga + (size_t)i * 32 * K + kt),
                                             LDP(&As[i * 2048 + tid * 8]), 16, 0, 0);
        #pragma unroll
        for (int i = 0; i < 2; ++i)
            __builtin_amdgcn_global_load_lds(GLP(gb + (size_t)i * 32 * K + kt),
                                             LDP(&Bs[i * 2048 + tid * 8]), 16, 0, 0);
        __syncthreads();

        bf16x8 af[2][4], bfr[2][2];
        #pragma unroll
        for (int t = 0; t < 4; ++t)
            #pragma unroll
            for (int kc = 0; kc < 2; ++kc)
                af[kc][t] = *(const bf16x8*)&As[(wm + t * 16 + l15) * 64
                                                + (((kc * 4 + lq) ^ e7) * 8)];
        #pragma unroll
        for (int t = 0; t < 2; ++t)
            #pragma unroll
            for (int kc = 0; kc < 2; ++kc)
                bfr[kc][t] = *(const bf16x8*)&Bs[(wn + t * 16 + l15) * 64
                                                 + (((kc * 4 + lq) ^ e7) * 8)];
        #pragma unroll
        for (int kc = 0; kc < 2; ++kc)
            #pragma unroll
            for (int mt = 0; mt < 4; ++mt)
                #pragma unroll
                for (int nt = 0; nt < 2; ++nt)
                    acc[mt][nt] = __builtin_amdgcn_mfma_f32_16x16x32_bf16(
                        af[kc][mt], bfr[kc][nt], acc[mt][nt], 0, 0, 0);
        __syncthreads();
    }

    float bv[2];
    #pragma unroll
    for (int nt = 0; nt < 2; ++nt) bv[nt] = bias[bn + wn + nt * 16 + l15];
    #pragma unroll
    for (int mt = 0; mt < 4; ++mt) {
        const int row = bm + wm + mt * 16 + lq * 4;
        #pragma unroll
        for (int nt = 0; nt < 2; ++nt) {
            const int col = bn + wn + nt * 16 + l15;
            #pragma unroll
            for (int r = 0; r < 4; ++r)
                Cm[(size_t)(row + r) * N + col] = acc[mt][nt][r] + bv[nt];
        }
    }
}

// ---------------------------------------------------------------------------
extern "C" void kernel_launch(void* const* d_in, const int* in_sizes, int n_in,
                              void* d_out, int out_size, void* d_ws, size_t ws_size,
                              hipStream_t stream)
{
    const float* x      = (const float*)d_in[0];
    const float* w_qkv  = (const float*)d_in[1];
    const float* w_proj = (const float*)d_in[2];
    const float* b_proj = (const float*)d_in[3];
    float*       out    = (float*)d_out;

    // workspace: 48 MiB
    unsigned short* xb     = (unsigned short*)d_ws;                 // [4096][1024]
    unsigned short* wqkvT  = xb     + (size_t)M_ROWS * C_DIM;       // [3072][1024]
    unsigned short* wprojT = wqkvT  + (size_t)QKV_N * C_DIM;        // [1024][1024]
    unsigned short* qbuf   = wprojT + (size_t)C_DIM * C_DIM;        // [32][2048][64]
    unsigned short* kbuf   = qbuf   + (size_t)M_ROWS * C_DIM;       // [32][2048][64]
    unsigned short* vbuf   = kbuf   + (size_t)M_ROWS * C_DIM;       // [32][64][2048]
    unsigned short* attnb  = vbuf   + (size_t)M_ROWS * C_DIM;       // [4096][1024]

    // 0) fused prep (x convert + both weight transposes)
    prep_fused<<<4096 + 768 + 256, 256, 0, stream>>>(x, xb, w_qkv, wqkvT, w_proj, wprojT);

    // 1) QKV projection (BK=64, conflict-free LDS, XCD-grouped 1D grid)
    gemm_qkv<<<768, 256, 0, stream>>>(xb, wqkvT, qbuf, kbuf, vbuf);

    // 2) flash attention (8 waves/block, 512 blocks, double-buffered)
    attn_mfma<<<512, 512, 0, stream>>>(qbuf, kbuf, vbuf, attnb);

    // 3) output projection + bias (BK=64, conflict-free LDS, fp32 out)
    gemm_bt<<<512, 256, 0, stream>>>(attnb, wprojT, b_proj, out, M_ROWS, C_DIM, C_DIM);
}